// Round 2
// baseline (2853.334 us; speedup 1.0000x reference)
//
#include <hip/hip_runtime.h>
#include <hip/hip_bf16.h>

// ---------------------------------------------------------------------------
// Round 8: de-serialize the encoder's weight stream.
//   Theory: R7 encoder was load-latency-bound (VGPR=64 -> no hoisting; every
//   MFMA stalled ~300cy on its L2 weight load; __syncthreads drained vmcnt).
//   Changes (encoder only):
//     - 8-deep register prefetch ring for the 48 weight chunks/step
//       (wes 0..15 then whh 0..31, consumed strictly in order)
//     - 4-deep ring for LDS A-fragments
//     - raw s_barrier + lgkmcnt(0) (NO vmcnt drain) so prefetch survives
//       the two per-step barriers
//     - schedule: attn+epi | barA | gates + aval | cell | barC
// ---------------------------------------------------------------------------

typedef unsigned short ushort_t;
using short4v = __attribute__((ext_vector_type(4))) short;   // 4 x bf16
using short8  = __attribute__((ext_vector_type(8))) short;   // 8 x bf16
using floatx4 = __attribute__((ext_vector_type(4))) float;   // MFMA accumulator

#define DEVFN static __device__ __forceinline__

DEVFN float bs2f(ushort_t u) {
    union { float f; unsigned v; } c; c.v = ((unsigned)u) << 16; return c.f;
}
DEVFN ushort_t f2bs(float f) {
    __hip_bfloat16 h = __float2bfloat16(f);
    return *reinterpret_cast<ushort_t*>(&h);
}
DEVFN float gload(const void* p, long i, int bf) {
    if (bf) return bs2f(((const ushort_t*)p)[i]);
    return ((const float*)p)[i];
}
DEVFN float sigm(float x) { return 1.f / (1.f + __expf(-x)); }
DEVFN float ftanh(float x) {
    float t = __expf(-2.f * fabsf(x));
    float r = (1.f - t) / (1.f + t);
    return copysignf(r, x);
}
DEVFN short8 ld8(const ushort_t* p) { return *reinterpret_cast<const short8*>(p); }

// write-side barrier: publish LDS writes, do NOT drain vmcnt (keep global
// prefetch in flight across the barrier)
DEVFN void bar_lgkm() {
    asm volatile("s_waitcnt lgkmcnt(0)" ::: "memory");
    __builtin_amdgcn_s_barrier();
}

struct SrcPtrs { const void* p[26]; };
struct WsPtrs {
    // wes/whh hold PERMUTED (fragment-major) data; wih holds PLAIN bf16
    // row-major Wih_e (GEMM input).
    ushort_t *wcfg, *bcfg, *eh, *ew, *es, *wis, *bis, *wes, *vds, *bvds,
             *whh, *wih, *bih, *bhh, *wdt, *bdt, *wd2t, *vdt, *bvdt,
             *wihd, *whhd, *bihd, *bhhd;
};

// ---------------------------------------------------------------------------
__global__ void k_detect(const void* probe, int* flag) {
    if (threadIdx.x == 0 && blockIdx.x == 0) {
        const ushort_t* u = (const ushort_t*)probe;
        int ok = 1;
        for (int i = 0; i < 16; ++i) {
            ushort_t v = u[2 * i];
            int e = (v >> 7) & 0xFF;
            if (!(v == 0 || (e >= 96 && e <= 126))) ok = 0;
        }
        *flag = ok;
    }
}

// ---------------------------------------------------------------------------
// k_cvt: small tensors only (wes/whh/wih are handled by the perm kernels).
// ---------------------------------------------------------------------------
__global__ __launch_bounds__(256) void k_cvt(SrcPtrs sp, WsPtrs wp, const int* flagp) {
    int bf = *flagp;
    const void* src = nullptr; ushort_t* dst = nullptr; long n = 0;
    switch (blockIdx.x) {
        case 0:  src = sp.p[3];  dst = wp.wcfg; n = 320;    break;
        case 1:  src = sp.p[4];  dst = wp.bcfg; n = 10;     break;
        case 2:  src = sp.p[5];  dst = wp.eh;   n = 120;    break;
        case 3:  src = sp.p[6];  dst = wp.ew;   n = 24;     break;
        case 4:  src = sp.p[7];  dst = wp.es;   n = 15;     break;
        case 5:  src = sp.p[16]; dst = wp.wis;  n = 65536;  break;
        case 6:  src = sp.p[17]; dst = wp.bis;  n = 256;    break;
        case 8:  src = sp.p[19]; dst = wp.vds;  n = 256;    break;
        case 9:  src = sp.p[20]; dst = wp.bvds; n = 1;      break;
        case 12: src = sp.p[10]; dst = wp.bih;  n = 1024;   break;
        case 13: src = sp.p[11]; dst = wp.bhh;  n = 1024;   break;
        case 14: src = sp.p[21]; dst = wp.wdt;  n = 65536;  break;
        case 15: src = sp.p[22]; dst = wp.bdt;  n = 256;    break;
        case 16: src = sp.p[23]; dst = wp.wd2t; n = 512;    break;
        case 17: src = sp.p[24]; dst = wp.vdt;  n = 256;    break;
        case 18: src = sp.p[25]; dst = wp.bvdt; n = 1;      break;
        case 19: src = sp.p[12]; dst = wp.wihd; n = 1028;   break;
        case 20: src = sp.p[13]; dst = wp.whhd; n = 4;      break;
        case 21: src = sp.p[14]; dst = wp.bihd; n = 4;      break;
        case 22: src = sp.p[15]; dst = wp.bhhd; n = 4;      break;
        default: return;
    }
    for (long i = threadIdx.x; i < n; i += 256) {
        float v = bf ? bs2f(((const ushort_t*)src)[i]) : ((const float*)src)[i];
        dst[i] = f2bs(v);
    }
}

// ---------------------------------------------------------------------------
// k_permA: y=0: Whh (1024x256 row-major) -> fragment-major (encoder layout).
//          y=1: Wih -> PLAIN bf16 copy (row-major; consumed by the AX GEMM).
// Fragment-major: dst p: chunk c=p>>9 (512 el = 64 lanes x 8), l=(p>>3)&63,
// e=p&7; c = w*32 + kk*4 + g; src row = g*256+w*16+(l&15),
// src col = kk*32+(l>>4)*8+e.  grid (128, 2), 2048 els/block.
// ---------------------------------------------------------------------------
__global__ __launch_bounds__(256) void k_permA(
    const void* whh_src, const void* wih_src,
    ushort_t* whhp, ushort_t* wihb, const int* flagp)
{
    int bf = *flagp;
    long base = (long)blockIdx.x * 2048;
    if (blockIdx.y == 1) {
#pragma unroll
        for (int ii = 0; ii < 8; ++ii) {
            long p = base + threadIdx.x + ii * 256;
            wihb[p] = f2bs(gload(wih_src, p, bf));
        }
        return;
    }
#pragma unroll
    for (int ii = 0; ii < 8; ++ii) {
        long p = base + threadIdx.x + ii * 256;
        int c = (int)(p >> 9), l = (int)((p >> 3) & 63), e = (int)(p & 7);
        int w = c >> 5, kk = (c >> 2) & 7, g = c & 3;
        int q = l >> 4, ln = l & 15;
        long si = (long)(g * 256 + w * 16 + ln) * 256 + kk * 32 + q * 8 + e;
        whhp[p] = f2bs(gload(whh_src, si, bf));
    }
}

// ---------------------------------------------------------------------------
// k_permB: Wes (256x512 row-major) -> fragment-major. c = w*16 + kk (kk 0..15).
// src row = w*16 + (l&15); src col = kk*32 + (l>>4)*8 + e. grid 64 blocks.
// ---------------------------------------------------------------------------
__global__ __launch_bounds__(256) void k_permB(
    const void* wes_src, ushort_t* wesp, const int* flagp)
{
    int bf = *flagp;
    long base = (long)blockIdx.x * 2048;
#pragma unroll
    for (int ii = 0; ii < 8; ++ii) {
        long p = base + threadIdx.x + ii * 256;
        int c = (int)(p >> 9), l = (int)((p >> 3) & 63), e = (int)(p & 7);
        int w = c >> 4, kk = c & 15;
        int q = l >> 4, ln = l & 15;
        long si = (long)(w * 16 + ln) * 512 + kk * 32 + q * 8 + e;
        wesp[p] = f2bs(gload(wes_src, si, bf));
    }
}

// ---------------------------------------------------------------------------
// k_build: features. 24576 blocks x 256 thr, 4 rows/block.
// ---------------------------------------------------------------------------
__global__ __launch_bounds__(256) void k_build(
    const void* __restrict__ pq, const void* __restrict__ cfg_in,
    const int* __restrict__ timei, WsPtrs wp, const int* __restrict__ flagp,
    ushort_t* __restrict__ inputs)
{
    int bf = *flagp;
    int ch = threadIdx.x;
    for (int rr = 0; rr < 4; ++rr) {
        long row = (long)blockIdx.x * 4 + rr;
        float v;
        if (ch < 235) {
            v = gload(pq, row * 235 + ch, bf);
        } else if (ch < 245) {
            int j = ch - 235;
            float acc = bs2f(wp.bcfg[j]);
            for (int k = 0; k < 32; ++k)
                acc += gload(cfg_in, row * 32 + k, bf) * bs2f(wp.wcfg[j * 32 + k]);
            v = acc;
        } else if (ch < 250) {
            v = bs2f(wp.eh[timei[row * 3 + 0] * 5 + (ch - 245)]);
        } else if (ch < 253) {
            v = bs2f(wp.ew[timei[row * 3 + 1] * 3 + (ch - 250)]);
        } else {
            v = bs2f(wp.es[timei[row * 3 + 2] * 3 + (ch - 253)]);
        }
        inputs[row * 256 + ch] = f2bs(v);
    }
}

// ---------------------------------------------------------------------------
// k_gemm: out = A @ W.T (+ bias). A:(98304x256), W row-major ws bf16, K=256.
// 128x128 tiles, BK=32, 4 waves of 64x64.
//   ostride : output row stride (256 for wi/wd, 1024 for AX)
//   gatherB : when set, output col c corresponds to W row (c&3)*256 + (c>>2)
//   bias==nullptr -> no bias.
// ---------------------------------------------------------------------------
__global__ __launch_bounds__(256) void k_gemm(
    const ushort_t* __restrict__ A, const ushort_t* __restrict__ W,
    const ushort_t* __restrict__ bias, ushort_t* __restrict__ out,
    int ostride, int gatherB)
{
    const int K = 256;
    __shared__ alignas(16) ushort_t At[128][40];
    __shared__ alignas(16) ushort_t Bt[128][40];

    int tid  = threadIdx.x;
    int lane = tid & 63, wave = tid >> 6;
    int wm = wave >> 1, wn = wave & 1;
    int q = lane >> 4, ln = lane & 15;
    long mbase = (long)blockIdx.x * 128;

    floatx4 acc[4][4];
#pragma unroll
    for (int i = 0; i < 4; ++i)
#pragma unroll
        for (int j = 0; j < 4; ++j) acc[i][j] = (floatx4){0.f, 0.f, 0.f, 0.f};

    for (int k0 = 0; k0 < K; k0 += 32) {
        __syncthreads();
#pragma unroll
        for (int it = 0; it < 2; ++it) {
            int c = tid + it * 256;
            int r = c >> 2, kc = (c & 3) * 8;
            int wrow = gatherB ? (((r & 3) << 8) + ((int)blockIdx.y << 5) + (r >> 2))
                               : ((int)blockIdx.y * 128 + r);
            *reinterpret_cast<short8*>(&At[r][kc]) = ld8(&A[(mbase + r) * K + k0 + kc]);
            *reinterpret_cast<short8*>(&Bt[r][kc]) = ld8(&W[(long)wrow * K + k0 + kc]);
        }
        __syncthreads();
        short8 af[4];
#pragma unroll
        for (int mt = 0; mt < 4; ++mt)
            af[mt] = *reinterpret_cast<const short8*>(&At[wm * 64 + mt * 16 + ln][q * 8]);
#pragma unroll
        for (int nt = 0; nt < 4; ++nt) {
            short8 bf = *reinterpret_cast<const short8*>(&Bt[wn * 64 + nt * 16 + ln][q * 8]);
#pragma unroll
            for (int mt = 0; mt < 4; ++mt)
                acc[mt][nt] = __builtin_amdgcn_mfma_f32_16x16x32_bf16(af[mt], bf, acc[mt][nt], 0, 0, 0);
        }
    }

#pragma unroll
    for (int mt = 0; mt < 4; ++mt)
#pragma unroll
        for (int nt = 0; nt < 4; ++nt)
#pragma unroll
            for (int reg = 0; reg < 4; ++reg) {
                long row = mbase + wm * 64 + mt * 16 + q * 4 + reg;
                int  col = (int)blockIdx.y * 128 + wn * 64 + nt * 16 + ln;
                float bv = bias ? bs2f(bias[col]) : 0.f;
                out[row * (long)ostride + col] = f2bs(acc[mt][nt][reg] + bv);
            }
}

// ---------------------------------------------------------------------------
// k_encoder: 64 blocks x 1024 thr (16 waves, 4/SIMD), 16 batch rows/block.
// Weight stream (48 x 1KB chunks/wave/step, always L2) pipelined through an
// 8-deep register ring; A-fragments through a 4-deep LDS ring. Raw barriers
// (lgkm drain only) keep global prefetch alive across sync points.
// Schedule: [mid(t-1) | ax/wi prefetch | attn MFMA + epi -> aPartT] barA
//           [gate MFMA || aval reads | cell -> Wb] barC
// ---------------------------------------------------------------------------
#define MFMA16(a, b, c) __builtin_amdgcn_mfma_f32_16x16x32_bf16((a), (b), (c), 0, 0, 0)

__global__ __launch_bounds__(1024, 4) void k_encoder(
    const ushort_t* __restrict__ wi, const ushort_t* __restrict__ ax,
    WsPtrs wp, ushort_t* __restrict__ mid)
{
    __shared__ alignas(16) ushort_t hcb[2][16][520];   // [h(0:256)|c(256:512)]
    __shared__ alignas(16) float aPartT[16][20];       // [wave][row]

    int tid  = threadIdx.x;
    int lane = tid & 63, w = tid >> 6;                 // w in [0,16)
    int q = lane >> 4, ln = lane & 15;
    int u = w * 16 + ln;                               // owned column
    long row0 = (long)blockIdx.x * 16;

    for (int i = tid; i < 2 * 16 * 520; i += 1024) ((ushort_t*)hcb)[i] = 0;

    // per-thread invariants
    float bc0 = bs2f(wp.bih[u])       + bs2f(wp.bhh[u]);
    float bc1 = bs2f(wp.bih[256 + u]) + bs2f(wp.bhh[256 + u]);
    float bc2 = bs2f(wp.bih[512 + u]) + bs2f(wp.bhh[512 + u]);
    float bc3 = bs2f(wp.bih[768 + u]) + bs2f(wp.bhh[768 + u]);
    float vds = bs2f(wp.vds[u]);
    float bVd = bs2f(wp.bvds[0]);

    const ushort_t* wesW = wp.wes + ((long)w << 13) + lane * 8;   // 16 chunks
    const ushort_t* whhW = wp.whh + ((long)w << 14) + lane * 8;   // 32 chunks

    const ushort_t* wiB[4]; const ushort_t* axB[4];
#pragma unroll
    for (int reg = 0; reg < 4; ++reg) {
        long rw = (row0 + q * 4 + reg) * 96;
        wiB[reg] = wi + rw * 256 + u;
        axB[reg] = ax + rw * 1024 + u * 4;
    }
    int mr = tid >> 6, mc = (tid & 63) * 4;            // mid-writer mapping
    ushort_t* midB = mid + (row0 + mr) * 96 * 256 + mc;

    float creg[4] = {0.f, 0.f, 0.f, 0.f};
    __syncthreads();

    for (int t = 0; t < 96; ++t) {
        ushort_t (*R)[520]  = hcb[t & 1];
        ushort_t (*Wb)[520] = hcb[(t & 1) ^ 1];

        // ---- coalesced mid write for step t-1 (reads R)
        if (t > 0) {
            uint2 hv = *reinterpret_cast<const uint2*>(&R[mr][mc]);
            *reinterpret_cast<uint2*>(midB + (long)(t - 1) * 256) = hv;
        }

        // ---- prefetch AX (4x8B) and wi (4x2B)
        short4v axv[4]; float wiv[4];
#pragma unroll
        for (int reg = 0; reg < 4; ++reg) {
            axv[reg] = *reinterpret_cast<const short4v*>(axB[reg] + (long)t * 1024);
            wiv[reg] = bs2f(wiB[reg][(long)t * 256]);
        }

        // ---- attn matvec: cols [w*16,w*16+16), K=512 over [h|c]
        // weight stream order: W[0..15]=wes, W[16..47]=whh; ring depth 8
        floatx4 acc1 = (floatx4){0.f, 0.f, 0.f, 0.f};
        short8 wring[8], aring[4];
#pragma unroll
        for (int j = 0; j < 8; ++j) wring[j] = ld8(wesW + (j << 9));
#pragma unroll
        for (int j = 0; j < 4; ++j)
            aring[j] = ld8(&R[ln][j * 32 + q * 8]);
#pragma unroll
        for (int kk = 0; kk < 16; ++kk) {
            short8 bw = wring[kk & 7];
            short8 af = aring[kk & 3];
            if (kk < 8) wring[kk & 7] = ld8(wesW + ((kk + 8) << 9));
            else        wring[kk & 7] = ld8(whhW + ((kk - 8) << 9));
            if (kk < 12) aring[kk & 3] = ld8(&R[ln][(kk + 4) * 32 + q * 8]);
            acc1 = MFMA16(af, bw, acc1);
        }

        // ---- attn epilogue: tanh, scale, reduce over 16 ln lanes
        float p4[4];
#pragma unroll
        for (int reg = 0; reg < 4; ++reg)
            p4[reg] = ftanh(acc1[reg] + wiv[reg]) * vds;
#pragma unroll
        for (int m = 1; m < 16; m <<= 1) {
#pragma unroll
            for (int reg = 0; reg < 4; ++reg) p4[reg] += __shfl_xor(p4[reg], m, 64);
        }
        if (ln == 0) {
            floatx4 pv = {p4[0], p4[1], p4[2], p4[3]};
            *reinterpret_cast<floatx4*>(&aPartT[w][q * 4]) = pv;
        }
        bar_lgkm();   // barrier A: aPartT visible (weight prefetch stays live)

        // ---- gate matvecs: aH = h@Whh.T (K=256); whh chunks 0..31 in order
        floatx4 aH[4];
#pragma unroll
        for (int g = 0; g < 4; ++g) aH[g] = (floatx4){0.f, 0.f, 0.f, 0.f};
        short8 ar2[4];
#pragma unroll
        for (int kk2 = 0; kk2 < 4; ++kk2)
            ar2[kk2] = ld8(&R[ln][kk2 * 32 + q * 8]);
#pragma unroll
        for (int kk = 0; kk < 8; ++kk) {
            short8 af = ar2[kk & 3];
            if (kk < 4) ar2[kk & 3] = ld8(&R[ln][(kk + 4) * 32 + q * 8]);
#pragma unroll
            for (int g = 0; g < 4; ++g) {
                int j = kk * 4 + g;
                short8 bw = wring[j & 7];
                if (j < 24) wring[j & 7] = ld8(whhW + ((j + 8) << 9));
                aH[g] = MFMA16(af, bw, aH[g]);
            }
        }

        // ---- aval: per-row sum of 16 wave partials (broadcast b128 reads,
        // overlaps the gate MFMAs)
        floatx4 av = {bVd, bVd, bVd, bVd};
#pragma unroll
        for (int ww = 0; ww < 16; ++ww)
            av += *reinterpret_cast<const floatx4*>(&aPartT[ww][q * 4]);

        // ---- cell update: rows q*4+reg, col u; write into Wb
#pragma unroll
        for (int reg = 0; reg < 4; ++reg) {
            float a  = av[reg];
            float gi = aH[0][reg] + a * bs2f((ushort_t)axv[reg][0]) + bc0;
            float gf = aH[1][reg] + a * bs2f((ushort_t)axv[reg][1]) + bc1;
            float gg = aH[2][reg] + a * bs2f((ushort_t)axv[reg][2]) + bc2;
            float go = aH[3][reg] + a * bs2f((ushort_t)axv[reg][3]) + bc3;
            float c2 = sigm(gf) * creg[reg] + sigm(gi) * ftanh(gg);
            float h2 = sigm(go) * ftanh(c2);
            creg[reg] = c2;
            int r = q * 4 + reg;
            Wb[r][u] = f2bs(h2);
            Wb[r][256 + u] = f2bs(c2);
        }
        bar_lgkm();   // barrier C: new state published
    }

    // final mid write: h_96 lives in hcb[0] (t=95 wrote buffer 0)
    {
        uint2 hv = *reinterpret_cast<const uint2*>(&hcb[0][mr][mc]);
        *reinterpret_cast<uint2*>(midB + 95L * 256) = hv;
    }
}

// ---------------------------------------------------------------------------
// k_decoder: 1024 blocks (one batch row), 256 thr, 16 sequential steps.
// ---------------------------------------------------------------------------
__global__ __launch_bounds__(256) void k_decoder(
    const ushort_t* __restrict__ mid, const ushort_t* __restrict__ wd,
    WsPtrs wp, const int* __restrict__ flagp, void* __restrict__ out)
{
    __shared__ ushort_t wdl[96][264];
    __shared__ float qL[256], aLs[96], ctxL[256], VdtL[256], gL[4];
    __shared__ float st[3];

    int tid = threadIdx.x;
    long b = blockIdx.x;
    int bf = *flagp;

    for (int c = tid; c < 96 * 256; c += 256) {
        int tp = c >> 8, chn = c & 255;
        wdl[tp][chn] = wd[(b * 96 + tp) * 256 + chn];
    }
    qL[tid] = 0.f; ctxL[tid] = 0.f;
    if (tid < 96) aLs[tid] = 0.f;
    if (tid < 4)  gL[tid] = 0.f;
    VdtL[tid] = bs2f(wp.vdt[tid]);
    if (tid == 0) {
        st[0] = 0.f; st[1] = 0.f;
        st[2] = bs2f(mid[(b * 96 + 95) * 256 + 2]);
    }
    float bVdt = bs2f(wp.bvdt[0]);
    float w2a = bs2f(wp.wd2t[tid * 2]), w2b = bs2f(wp.wd2t[tid * 2 + 1]);
    __syncthreads();

    for (int s = 0; s < 16; ++s) {
        float hi = st[0], ci = st[1], prev = st[2];
        qL[tid] = hi * w2a + ci * w2b;
        __syncthreads();
        {   // attn scores: wave v, lanes split the 256-dot
            int v = tid >> 6, l = tid & 63;
            for (int tp = v; tp < 96; tp += 4) {
                float sacc = 0.f;
#pragma unroll
                for (int e = 0; e < 4; ++e) {
                    int u = l * 4 + e;
                    sacc += ftanh(qL[u] + bs2f(wdl[tp][u])) * VdtL[u];
                }
#pragma unroll
                for (int m = 1; m < 64; m <<= 1) sacc += __shfl_xor(sacc, m, 64);
                if (l == 0) aLs[tp] = sacc + bVdt;
            }
        }
        __syncthreads();
        {
            float acc = 0.f;
            for (int tp = 0; tp < 96; ++tp)
                acc += aLs[tp] * bs2f(mid[(b * 96 + tp) * 256 + tid]);
            ctxL[tid] = acc;
        }
        __syncthreads();
        {   // gates: wave g computes gate g; lanes split the ctx-dot
            int g = tid >> 6, k = tid & 63;
            float part = 0.f;
#pragma unroll
            for (int e = 0; e < 4; ++e) {
                int u = k + e * 64;
                part += bs2f(wp.wihd[g * 257 + u]) * ctxL[u];
            }
#pragma unroll
            for (int m = 1; m < 64; m <<= 1) part += __shfl_xor(part, m, 64);
            if (k == 0)
                gL[g] = part + bs2f(wp.bihd[g]) + bs2f(wp.bhhd[g])
                      + bs2f(wp.whhd[g]) * hi + bs2f(wp.wihd[g * 257 + 256]) * prev;
        }
        __syncthreads();
        if (tid == 0) {
            float c2 = sigm(gL[1]) * ci + sigm(gL[0]) * ftanh(gL[2]);
            float h2 = sigm(gL[3]) * ftanh(c2);
            st[0] = h2; st[1] = c2; st[2] = h2;
            long oi = b * 16 + s;
            if (bf) ((ushort_t*)out)[oi] = f2bs(h2);
            else    ((float*)out)[oi] = h2;
        }
        __syncthreads();
    }
}

// ---------------------------------------------------------------------------
extern "C" void kernel_launch(void* const* d_in, const int* in_sizes, int n_in,
                              void* d_out, int out_size, void* d_ws, size_t ws_size,
                              hipStream_t stream)
{
    const long MT = 1024L * 96;   // 98304 rows

    int* flagp = (int*)d_ws;
    ushort_t* base = (ushort_t*)((char*)d_ws + 256);

    SrcPtrs sp;
    for (int i = 0; i < 26; ++i) sp.p[i] = d_in[i];

    static const long sizes[23] = {
        320, 10, 120, 24, 15, 65536, 256, 131072, 256, 1,
        262144, 262144, 1024, 1024, 65536, 256, 512, 256, 1,
        1028, 4, 4, 4
    };
    ushort_t* ptrs[23];
    long off = 0;
    for (int i = 0; i < 23; ++i) {
        ptrs[i] = base + off;
        off += (sizes[i] + 7) & ~7L;   // 16B-aligned layout
    }

    WsPtrs wp;
    wp.wcfg = ptrs[0];  wp.bcfg = ptrs[1];  wp.eh   = ptrs[2];  wp.ew   = ptrs[3];
    wp.es   = ptrs[4];  wp.wis  = ptrs[5];  wp.bis  = ptrs[6];  wp.wes  = ptrs[7];
    wp.vds  = ptrs[8];  wp.bvds = ptrs[9];  wp.whh  = ptrs[10]; wp.wih  = ptrs[11];
    wp.bih  = ptrs[12]; wp.bhh  = ptrs[13]; wp.wdt  = ptrs[14]; wp.bdt  = ptrs[15];
    wp.wd2t = ptrs[16]; wp.vdt  = ptrs[17]; wp.bvdt = ptrs[18]; wp.wihd = ptrs[19];
    wp.whhd = ptrs[20]; wp.bihd = ptrs[21]; wp.bhhd = ptrs[22];

    ushort_t* inputs = base + off;            // MT*256
    ushort_t* wib    = inputs + MT * 256;     // MT*256
    ushort_t* midb   = wib + MT * 256;        // MT*256
    ushort_t* axb    = midb + MT * 256;       // MT*1024 (201 MB): AX = x@Wih.T
    ushort_t* wdb    = wib;                   // alias: wi dead after encoder

    k_detect<<<1, 64, 0, stream>>>(d_in[3], flagp);
    k_cvt<<<23, 256, 0, stream>>>(sp, wp, flagp);
    k_permA<<<dim3(128, 2), 256, 0, stream>>>(d_in[9], d_in[8], wp.whh, wp.wih, flagp);
    k_permB<<<64, 256, 0, stream>>>(d_in[18], wp.wes, flagp);
    k_build<<<24576, 256, 0, stream>>>(d_in[0], d_in[1], (const int*)d_in[2],
                                       wp, flagp, inputs);
    k_gemm<<<dim3(768, 2), 256, 0, stream>>>(inputs, wp.wis, wp.bis, wib, 256, 0);
    k_gemm<<<dim3(768, 8), 256, 0, stream>>>(inputs, wp.wih, nullptr, axb, 1024, 1);
    k_encoder<<<64, 1024, 0, stream>>>(wib, axb, wp, midb);
    k_gemm<<<dim3(768, 2), 256, 0, stream>>>(midb, wp.wdt, wp.bdt, wdb, 256, 0);
    k_decoder<<<1024, 256, 0, stream>>>(midb, wdb, wp, flagp, d_out);
}

// Round 3
// 2802.031 us; speedup vs baseline: 1.0183x; 1.0183x over previous
//
#include <hip/hip_runtime.h>
#include <hip/hip_bf16.h>

// ---------------------------------------------------------------------------
// Round 9: pin waves/EU=4 (128-VGPR budget) + 2-batch register-pipelined
// weight stream in the encoder.
//   Root cause of R7/R8's VGPR=64: launch_bounds(1024,4) only sets MIN
//   waves/EU; with 34KB LDS the compiler targeted 2 blocks/CU (8 waves/EU)
//   and register-starved the loop, serializing the 48x1KB/wave/step weight
//   stream (~790cy per chunk, un-overlapped -> 40k cy/step).
//   Fix: amdgpu_waves_per_eu(4,4) + explicit WA/WB batches (64 VGPRs) that
//   cycle through the step-invariant chunk stream wes0-15,whh0-31 with
//   cross-step, cross-barrier lookahead (lgkm-only barriers keep loads live).
// ---------------------------------------------------------------------------

typedef unsigned short ushort_t;
using short4v = __attribute__((ext_vector_type(4))) short;   // 4 x bf16
using short8  = __attribute__((ext_vector_type(8))) short;   // 8 x bf16
using floatx4 = __attribute__((ext_vector_type(4))) float;   // MFMA accumulator

#define DEVFN static __device__ __forceinline__

DEVFN float bs2f(ushort_t u) {
    union { float f; unsigned v; } c; c.v = ((unsigned)u) << 16; return c.f;
}
DEVFN ushort_t f2bs(float f) {
    __hip_bfloat16 h = __float2bfloat16(f);
    return *reinterpret_cast<ushort_t*>(&h);
}
DEVFN float gload(const void* p, long i, int bf) {
    if (bf) return bs2f(((const ushort_t*)p)[i]);
    return ((const float*)p)[i];
}
DEVFN float sigm(float x) { return 1.f / (1.f + __expf(-x)); }
DEVFN float ftanh(float x) {
    float t = __expf(-2.f * fabsf(x));
    float r = (1.f - t) / (1.f + t);
    return copysignf(r, x);
}
DEVFN short8 ld8(const ushort_t* p) { return *reinterpret_cast<const short8*>(p); }

// publish LDS writes + barrier, WITHOUT draining vmcnt (global prefetch
// stays in flight across the barrier)
DEVFN void bar_lgkm() {
    asm volatile("s_waitcnt lgkmcnt(0)" ::: "memory");
    __builtin_amdgcn_s_barrier();
}

struct SrcPtrs { const void* p[26]; };
struct WsPtrs {
    // wes/whh hold PERMUTED (fragment-major) data; wih holds PLAIN bf16
    // row-major Wih_e (GEMM input).
    ushort_t *wcfg, *bcfg, *eh, *ew, *es, *wis, *bis, *wes, *vds, *bvds,
             *whh, *wih, *bih, *bhh, *wdt, *bdt, *wd2t, *vdt, *bvdt,
             *wihd, *whhd, *bihd, *bhhd;
};

// ---------------------------------------------------------------------------
__global__ void k_detect(const void* probe, int* flag) {
    if (threadIdx.x == 0 && blockIdx.x == 0) {
        const ushort_t* u = (const ushort_t*)probe;
        int ok = 1;
        for (int i = 0; i < 16; ++i) {
            ushort_t v = u[2 * i];
            int e = (v >> 7) & 0xFF;
            if (!(v == 0 || (e >= 96 && e <= 126))) ok = 0;
        }
        *flag = ok;
    }
}

// ---------------------------------------------------------------------------
// k_cvt: small tensors only (wes/whh/wih are handled by the perm kernels).
// ---------------------------------------------------------------------------
__global__ __launch_bounds__(256) void k_cvt(SrcPtrs sp, WsPtrs wp, const int* flagp) {
    int bf = *flagp;
    const void* src = nullptr; ushort_t* dst = nullptr; long n = 0;
    switch (blockIdx.x) {
        case 0:  src = sp.p[3];  dst = wp.wcfg; n = 320;    break;
        case 1:  src = sp.p[4];  dst = wp.bcfg; n = 10;     break;
        case 2:  src = sp.p[5];  dst = wp.eh;   n = 120;    break;
        case 3:  src = sp.p[6];  dst = wp.ew;   n = 24;     break;
        case 4:  src = sp.p[7];  dst = wp.es;   n = 15;     break;
        case 5:  src = sp.p[16]; dst = wp.wis;  n = 65536;  break;
        case 6:  src = sp.p[17]; dst = wp.bis;  n = 256;    break;
        case 8:  src = sp.p[19]; dst = wp.vds;  n = 256;    break;
        case 9:  src = sp.p[20]; dst = wp.bvds; n = 1;      break;
        case 12: src = sp.p[10]; dst = wp.bih;  n = 1024;   break;
        case 13: src = sp.p[11]; dst = wp.bhh;  n = 1024;   break;
        case 14: src = sp.p[21]; dst = wp.wdt;  n = 65536;  break;
        case 15: src = sp.p[22]; dst = wp.bdt;  n = 256;    break;
        case 16: src = sp.p[23]; dst = wp.wd2t; n = 512;    break;
        case 17: src = sp.p[24]; dst = wp.vdt;  n = 256;    break;
        case 18: src = sp.p[25]; dst = wp.bvdt; n = 1;      break;
        case 19: src = sp.p[12]; dst = wp.wihd; n = 1028;   break;
        case 20: src = sp.p[13]; dst = wp.whhd; n = 4;      break;
        case 21: src = sp.p[14]; dst = wp.bihd; n = 4;      break;
        case 22: src = sp.p[15]; dst = wp.bhhd; n = 4;      break;
        default: return;
    }
    for (long i = threadIdx.x; i < n; i += 256) {
        float v = bf ? bs2f(((const ushort_t*)src)[i]) : ((const float*)src)[i];
        dst[i] = f2bs(v);
    }
}

// ---------------------------------------------------------------------------
// k_permA: y=0: Whh (1024x256 row-major) -> fragment-major (encoder layout).
//          y=1: Wih -> PLAIN bf16 copy (row-major; consumed by the AX GEMM).
// Fragment-major: dst p: chunk c=p>>9 (512 el = 64 lanes x 8), l=(p>>3)&63,
// e=p&7; c = w*32 + kk*4 + g; src row = g*256+w*16+(l&15),
// src col = kk*32+(l>>4)*8+e.  grid (128, 2), 2048 els/block.
// ---------------------------------------------------------------------------
__global__ __launch_bounds__(256) void k_permA(
    const void* whh_src, const void* wih_src,
    ushort_t* whhp, ushort_t* wihb, const int* flagp)
{
    int bf = *flagp;
    long base = (long)blockIdx.x * 2048;
    if (blockIdx.y == 1) {
#pragma unroll
        for (int ii = 0; ii < 8; ++ii) {
            long p = base + threadIdx.x + ii * 256;
            wihb[p] = f2bs(gload(wih_src, p, bf));
        }
        return;
    }
#pragma unroll
    for (int ii = 0; ii < 8; ++ii) {
        long p = base + threadIdx.x + ii * 256;
        int c = (int)(p >> 9), l = (int)((p >> 3) & 63), e = (int)(p & 7);
        int w = c >> 5, kk = (c >> 2) & 7, g = c & 3;
        int q = l >> 4, ln = l & 15;
        long si = (long)(g * 256 + w * 16 + ln) * 256 + kk * 32 + q * 8 + e;
        whhp[p] = f2bs(gload(whh_src, si, bf));
    }
}

// ---------------------------------------------------------------------------
// k_permB: Wes (256x512 row-major) -> fragment-major. c = w*16 + kk (kk 0..15).
// src row = w*16 + (l&15); src col = kk*32 + (l>>4)*8 + e. grid 64 blocks.
// ---------------------------------------------------------------------------
__global__ __launch_bounds__(256) void k_permB(
    const void* wes_src, ushort_t* wesp, const int* flagp)
{
    int bf = *flagp;
    long base = (long)blockIdx.x * 2048;
#pragma unroll
    for (int ii = 0; ii < 8; ++ii) {
        long p = base + threadIdx.x + ii * 256;
        int c = (int)(p >> 9), l = (int)((p >> 3) & 63), e = (int)(p & 7);
        int w = c >> 4, kk = c & 15;
        int q = l >> 4, ln = l & 15;
        long si = (long)(w * 16 + ln) * 512 + kk * 32 + q * 8 + e;
        wesp[p] = f2bs(gload(wes_src, si, bf));
    }
}

// ---------------------------------------------------------------------------
// k_build: features. 24576 blocks x 256 thr, 4 rows/block.
// ---------------------------------------------------------------------------
__global__ __launch_bounds__(256) void k_build(
    const void* __restrict__ pq, const void* __restrict__ cfg_in,
    const int* __restrict__ timei, WsPtrs wp, const int* __restrict__ flagp,
    ushort_t* __restrict__ inputs)
{
    int bf = *flagp;
    int ch = threadIdx.x;
    for (int rr = 0; rr < 4; ++rr) {
        long row = (long)blockIdx.x * 4 + rr;
        float v;
        if (ch < 235) {
            v = gload(pq, row * 235 + ch, bf);
        } else if (ch < 245) {
            int j = ch - 235;
            float acc = bs2f(wp.bcfg[j]);
            for (int k = 0; k < 32; ++k)
                acc += gload(cfg_in, row * 32 + k, bf) * bs2f(wp.wcfg[j * 32 + k]);
            v = acc;
        } else if (ch < 250) {
            v = bs2f(wp.eh[timei[row * 3 + 0] * 5 + (ch - 245)]);
        } else if (ch < 253) {
            v = bs2f(wp.ew[timei[row * 3 + 1] * 3 + (ch - 250)]);
        } else {
            v = bs2f(wp.es[timei[row * 3 + 2] * 3 + (ch - 253)]);
        }
        inputs[row * 256 + ch] = f2bs(v);
    }
}

// ---------------------------------------------------------------------------
// k_gemm: out = A @ W.T (+ bias). A:(98304x256), W row-major ws bf16, K=256.
// 128x128 tiles, BK=32, 4 waves of 64x64.
//   ostride : output row stride (256 for wi/wd, 1024 for AX)
//   gatherB : when set, output col c corresponds to W row (c&3)*256 + (c>>2)
//   bias==nullptr -> no bias.
// ---------------------------------------------------------------------------
__global__ __launch_bounds__(256) void k_gemm(
    const ushort_t* __restrict__ A, const ushort_t* __restrict__ W,
    const ushort_t* __restrict__ bias, ushort_t* __restrict__ out,
    int ostride, int gatherB)
{
    const int K = 256;
    __shared__ alignas(16) ushort_t At[128][40];
    __shared__ alignas(16) ushort_t Bt[128][40];

    int tid  = threadIdx.x;
    int lane = tid & 63, wave = tid >> 6;
    int wm = wave >> 1, wn = wave & 1;
    int q = lane >> 4, ln = lane & 15;
    long mbase = (long)blockIdx.x * 128;

    floatx4 acc[4][4];
#pragma unroll
    for (int i = 0; i < 4; ++i)
#pragma unroll
        for (int j = 0; j < 4; ++j) acc[i][j] = (floatx4){0.f, 0.f, 0.f, 0.f};

    for (int k0 = 0; k0 < K; k0 += 32) {
        __syncthreads();
#pragma unroll
        for (int it = 0; it < 2; ++it) {
            int c = tid + it * 256;
            int r = c >> 2, kc = (c & 3) * 8;
            int wrow = gatherB ? (((r & 3) << 8) + ((int)blockIdx.y << 5) + (r >> 2))
                               : ((int)blockIdx.y * 128 + r);
            *reinterpret_cast<short8*>(&At[r][kc]) = ld8(&A[(mbase + r) * K + k0 + kc]);
            *reinterpret_cast<short8*>(&Bt[r][kc]) = ld8(&W[(long)wrow * K + k0 + kc]);
        }
        __syncthreads();
        short8 af[4];
#pragma unroll
        for (int mt = 0; mt < 4; ++mt)
            af[mt] = *reinterpret_cast<const short8*>(&At[wm * 64 + mt * 16 + ln][q * 8]);
#pragma unroll
        for (int nt = 0; nt < 4; ++nt) {
            short8 bf = *reinterpret_cast<const short8*>(&Bt[wn * 64 + nt * 16 + ln][q * 8]);
#pragma unroll
            for (int mt = 0; mt < 4; ++mt)
                acc[mt][nt] = __builtin_amdgcn_mfma_f32_16x16x32_bf16(af[mt], bf, acc[mt][nt], 0, 0, 0);
        }
    }

#pragma unroll
    for (int mt = 0; mt < 4; ++mt)
#pragma unroll
        for (int nt = 0; nt < 4; ++nt)
#pragma unroll
            for (int reg = 0; reg < 4; ++reg) {
                long row = mbase + wm * 64 + mt * 16 + q * 4 + reg;
                int  col = (int)blockIdx.y * 128 + wn * 64 + nt * 16 + ln;
                float bv = bias ? bs2f(bias[col]) : 0.f;
                out[row * (long)ostride + col] = f2bs(acc[mt][nt][reg] + bv);
            }
}

// ---------------------------------------------------------------------------
// k_encoder: 64 blocks x 1024 thr (16 waves, EXACTLY 4/SIMD), 16 rows/block.
// Weight stream: cyclic 48x1KB chunks/wave/step (wes0-15 whh0-31), held in
// two 8-chunk register batches WA/WB (64 VGPRs). Refills are issued 1.5-2
// batches ahead of consumption and cross both barriers and the step boundary
// (addresses are step-invariant; lgkm-only barriers never drain vmcnt).
// Schedule: [mid(t-1)|ax/wi pre|attn: WA,refill,WB,refill|epi] barA
//           [gates: q1 WA,refill | q2 WB,refill | q3 WA,refill(wes0-7 t+1)
//            | q4 WB,refill(wes8-15 t+1) || aval | cell] barC
// ---------------------------------------------------------------------------
#define MFMA16(a, b, c) __builtin_amdgcn_mfma_f32_16x16x32_bf16((a), (b), (c), 0, 0, 0)

__global__ __launch_bounds__(1024) __attribute__((amdgpu_waves_per_eu(4, 4)))
void k_encoder(
    const ushort_t* __restrict__ wi, const ushort_t* __restrict__ ax,
    WsPtrs wp, ushort_t* __restrict__ mid)
{
    __shared__ alignas(16) ushort_t hcb[2][16][520];   // [h(0:256)|c(256:512)]
    __shared__ alignas(16) float aPartT[16][20];       // [wave][row]

    int tid  = threadIdx.x;
    int lane = tid & 63, w = tid >> 6;                 // w in [0,16)
    int q = lane >> 4, ln = lane & 15;
    int u = w * 16 + ln;                               // owned column
    long row0 = (long)blockIdx.x * 16;

    for (int i = tid; i < 2 * 16 * 520; i += 1024) ((ushort_t*)hcb)[i] = 0;

    // per-thread invariants
    float bc0 = bs2f(wp.bih[u])       + bs2f(wp.bhh[u]);
    float bc1 = bs2f(wp.bih[256 + u]) + bs2f(wp.bhh[256 + u]);
    float bc2 = bs2f(wp.bih[512 + u]) + bs2f(wp.bhh[512 + u]);
    float bc3 = bs2f(wp.bih[768 + u]) + bs2f(wp.bhh[768 + u]);
    float vds = bs2f(wp.vds[u]);
    float bVd = bs2f(wp.bvds[0]);

    const ushort_t* wesW = wp.wes + ((long)w << 13) + lane * 8;   // 16 chunks
    const ushort_t* whhW = wp.whh + ((long)w << 14) + lane * 8;   // 32 chunks

    const ushort_t* wiB[4]; const ushort_t* axB[4];
#pragma unroll
    for (int reg = 0; reg < 4; ++reg) {
        long rw = (row0 + q * 4 + reg) * 96;
        wiB[reg] = wi + rw * 256 + u;
        axB[reg] = ax + rw * 1024 + u * 4;
    }
    int mr = tid >> 6, mc = (tid & 63) * 4;            // mid-writer mapping
    ushort_t* midB = mid + (row0 + mr) * 96 * 256 + mc;

    float creg[4] = {0.f, 0.f, 0.f, 0.f};
    __syncthreads();

    // ---- weight stream prologue: WA = wes0-7, WB = wes8-15
    short8 WA[8], WB[8];
#pragma unroll
    for (int j = 0; j < 8; ++j) WA[j] = ld8(wesW + (j << 9));
#pragma unroll
    for (int j = 0; j < 8; ++j) WB[j] = ld8(wesW + ((j + 8) << 9));

    for (int t = 0; t < 96; ++t) {
        ushort_t (*R)[520]  = hcb[t & 1];
        ushort_t (*Wb)[520] = hcb[(t & 1) ^ 1];

        // ---- coalesced mid write for step t-1 (reads R)
        if (t > 0) {
            uint2 hv = *reinterpret_cast<const uint2*>(&R[mr][mc]);
            *reinterpret_cast<uint2*>(midB + (long)(t - 1) * 256) = hv;
        }

        // ---- prefetch AX (4x8B) and wi (4x2B); consumed at end of step
        short4v axv[4]; float wiv[4];
#pragma unroll
        for (int reg = 0; reg < 4; ++reg) {
            axv[reg] = *reinterpret_cast<const short4v*>(axB[reg] + (long)t * 1024);
            wiv[reg] = bs2f(wiB[reg][(long)t * 256]);
        }

        // ---- attn matvec: K=512 over [h|c]; consume WA(wes0-7), WB(wes8-15)
        floatx4 acc1 = (floatx4){0.f, 0.f, 0.f, 0.f};
#pragma unroll
        for (int kk = 0; kk < 8; ++kk) {
            short8 af = *reinterpret_cast<const short8*>(&R[ln][kk * 32 + q * 8]);
            acc1 = MFMA16(af, WA[kk], acc1);
        }
#pragma unroll
        for (int j = 0; j < 8; ++j) WA[j] = ld8(whhW + (j << 9));       // whh0-7
#pragma unroll
        for (int kk = 0; kk < 8; ++kk) {
            short8 af = *reinterpret_cast<const short8*>(&R[ln][(kk + 8) * 32 + q * 8]);
            acc1 = MFMA16(af, WB[kk], acc1);
        }
#pragma unroll
        for (int j = 0; j < 8; ++j) WB[j] = ld8(whhW + ((j + 8) << 9)); // whh8-15

        // ---- attn epilogue: tanh, scale, reduce over 16 ln lanes
        float p4[4];
#pragma unroll
        for (int reg = 0; reg < 4; ++reg)
            p4[reg] = ftanh(acc1[reg] + wiv[reg]) * vds;
#pragma unroll
        for (int m = 1; m < 16; m <<= 1) {
#pragma unroll
            for (int reg = 0; reg < 4; ++reg) p4[reg] += __shfl_xor(p4[reg], m, 64);
        }
        if (ln == 0) {
            floatx4 pv = {p4[0], p4[1], p4[2], p4[3]};
            *reinterpret_cast<floatx4*>(&aPartT[w][q * 4]) = pv;
        }
        bar_lgkm();   // barrier A: aPartT visible (weight prefetch stays live)

        // ---- gates: aH = h@Whh.T; chunk(kk,g) = kk*4+g
        floatx4 aH[4];
#pragma unroll
        for (int g = 0; g < 4; ++g) aH[g] = (floatx4){0.f, 0.f, 0.f, 0.f};

        // q1: kk=0,1 consume WA (whh0-7); refill WA <- whh16-23
#pragma unroll
        for (int kk = 0; kk < 2; ++kk) {
            short8 af = *reinterpret_cast<const short8*>(&R[ln][kk * 32 + q * 8]);
#pragma unroll
            for (int g = 0; g < 4; ++g) aH[g] = MFMA16(af, WA[kk * 4 + g], aH[g]);
        }
#pragma unroll
        for (int j = 0; j < 8; ++j) WA[j] = ld8(whhW + ((16 + j) << 9));
        // q2: kk=2,3 consume WB (whh8-15); refill WB <- whh24-31
#pragma unroll
        for (int kk = 2; kk < 4; ++kk) {
            short8 af = *reinterpret_cast<const short8*>(&R[ln][kk * 32 + q * 8]);
#pragma unroll
            for (int g = 0; g < 4; ++g) aH[g] = MFMA16(af, WB[(kk - 2) * 4 + g], aH[g]);
        }
#pragma unroll
        for (int j = 0; j < 8; ++j) WB[j] = ld8(whhW + ((24 + j) << 9));
        // q3: kk=4,5 consume WA (whh16-23); refill WA <- wes0-7 (next step)
#pragma unroll
        for (int kk = 4; kk < 6; ++kk) {
            short8 af = *reinterpret_cast<const short8*>(&R[ln][kk * 32 + q * 8]);
#pragma unroll
            for (int g = 0; g < 4; ++g) aH[g] = MFMA16(af, WA[(kk - 4) * 4 + g], aH[g]);
        }
#pragma unroll
        for (int j = 0; j < 8; ++j) WA[j] = ld8(wesW + (j << 9));
        // q4: kk=6,7 consume WB (whh24-31); refill WB <- wes8-15 (next step)
#pragma unroll
        for (int kk = 6; kk < 8; ++kk) {
            short8 af = *reinterpret_cast<const short8*>(&R[ln][kk * 32 + q * 8]);
#pragma unroll
            for (int g = 0; g < 4; ++g) aH[g] = MFMA16(af, WB[(kk - 6) * 4 + g], aH[g]);
        }
#pragma unroll
        for (int j = 0; j < 8; ++j) WB[j] = ld8(wesW + ((j + 8) << 9));

        // ---- aval: per-row sum of 16 wave partials (broadcast b128 reads)
        floatx4 av = {bVd, bVd, bVd, bVd};
#pragma unroll
        for (int ww = 0; ww < 16; ++ww)
            av += *reinterpret_cast<const floatx4*>(&aPartT[ww][q * 4]);

        // ---- cell update: rows q*4+reg, col u; write into Wb
#pragma unroll
        for (int reg = 0; reg < 4; ++reg) {
            float a  = av[reg];
            float gi = aH[0][reg] + a * bs2f((ushort_t)axv[reg][0]) + bc0;
            float gf = aH[1][reg] + a * bs2f((ushort_t)axv[reg][1]) + bc1;
            float gg = aH[2][reg] + a * bs2f((ushort_t)axv[reg][2]) + bc2;
            float go = aH[3][reg] + a * bs2f((ushort_t)axv[reg][3]) + bc3;
            float c2 = sigm(gf) * creg[reg] + sigm(gi) * ftanh(gg);
            float h2 = sigm(go) * ftanh(c2);
            creg[reg] = c2;
            int r = q * 4 + reg;
            Wb[r][u] = f2bs(h2);
            Wb[r][256 + u] = f2bs(c2);
        }
        bar_lgkm();   // barrier C: new state published
    }

    // final mid write: h_96 lives in hcb[0] (t=95 wrote buffer 0)
    {
        uint2 hv = *reinterpret_cast<const uint2*>(&hcb[0][mr][mc]);
        *reinterpret_cast<uint2*>(midB + 95L * 256) = hv;
    }
}

// ---------------------------------------------------------------------------
// k_decoder: 1024 blocks (one batch row), 256 thr, 16 sequential steps.
// ---------------------------------------------------------------------------
__global__ __launch_bounds__(256) void k_decoder(
    const ushort_t* __restrict__ mid, const ushort_t* __restrict__ wd,
    WsPtrs wp, const int* __restrict__ flagp, void* __restrict__ out)
{
    __shared__ ushort_t wdl[96][264];
    __shared__ float qL[256], aLs[96], ctxL[256], VdtL[256], gL[4];
    __shared__ float st[3];

    int tid = threadIdx.x;
    long b = blockIdx.x;
    int bf = *flagp;

    for (int c = tid; c < 96 * 256; c += 256) {
        int tp = c >> 8, chn = c & 255;
        wdl[tp][chn] = wd[(b * 96 + tp) * 256 + chn];
    }
    qL[tid] = 0.f; ctxL[tid] = 0.f;
    if (tid < 96) aLs[tid] = 0.f;
    if (tid < 4)  gL[tid] = 0.f;
    VdtL[tid] = bs2f(wp.vdt[tid]);
    if (tid == 0) {
        st[0] = 0.f; st[1] = 0.f;
        st[2] = bs2f(mid[(b * 96 + 95) * 256 + 2]);
    }
    float bVdt = bs2f(wp.bvdt[0]);
    float w2a = bs2f(wp.wd2t[tid * 2]), w2b = bs2f(wp.wd2t[tid * 2 + 1]);
    __syncthreads();

    for (int s = 0; s < 16; ++s) {
        float hi = st[0], ci = st[1], prev = st[2];
        qL[tid] = hi * w2a + ci * w2b;
        __syncthreads();
        {   // attn scores: wave v, lanes split the 256-dot
            int v = tid >> 6, l = tid & 63;
            for (int tp = v; tp < 96; tp += 4) {
                float sacc = 0.f;
#pragma unroll
                for (int e = 0; e < 4; ++e) {
                    int u = l * 4 + e;
                    sacc += ftanh(qL[u] + bs2f(wdl[tp][u])) * VdtL[u];
                }
#pragma unroll
                for (int m = 1; m < 64; m <<= 1) sacc += __shfl_xor(sacc, m, 64);
                if (l == 0) aLs[tp] = sacc + bVdt;
            }
        }
        __syncthreads();
        {
            float acc = 0.f;
            for (int tp = 0; tp < 96; ++tp)
                acc += aLs[tp] * bs2f(mid[(b * 96 + tp) * 256 + tid]);
            ctxL[tid] = acc;
        }
        __syncthreads();
        {   // gates: wave g computes gate g; lanes split the ctx-dot
            int g = tid >> 6, k = tid & 63;
            float part = 0.f;
#pragma unroll
            for (int e = 0; e < 4; ++e) {
                int u = k + e * 64;
                part += bs2f(wp.wihd[g * 257 + u]) * ctxL[u];
            }
#pragma unroll
            for (int m = 1; m < 64; m <<= 1) part += __shfl_xor(part, m, 64);
            if (k == 0)
                gL[g] = part + bs2f(wp.bihd[g]) + bs2f(wp.bhhd[g])
                      + bs2f(wp.whhd[g]) * hi + bs2f(wp.wihd[g * 257 + 256]) * prev;
        }
        __syncthreads();
        if (tid == 0) {
            float c2 = sigm(gL[1]) * ci + sigm(gL[0]) * ftanh(gL[2]);
            float h2 = sigm(gL[3]) * ftanh(c2);
            st[0] = h2; st[1] = c2; st[2] = h2;
            long oi = b * 16 + s;
            if (bf) ((ushort_t*)out)[oi] = f2bs(h2);
            else    ((float*)out)[oi] = h2;
        }
        __syncthreads();
    }
}

// ---------------------------------------------------------------------------
extern "C" void kernel_launch(void* const* d_in, const int* in_sizes, int n_in,
                              void* d_out, int out_size, void* d_ws, size_t ws_size,
                              hipStream_t stream)
{
    const long MT = 1024L * 96;   // 98304 rows

    int* flagp = (int*)d_ws;
    ushort_t* base = (ushort_t*)((char*)d_ws + 256);

    SrcPtrs sp;
    for (int i = 0; i < 26; ++i) sp.p[i] = d_in[i];

    static const long sizes[23] = {
        320, 10, 120, 24, 15, 65536, 256, 131072, 256, 1,
        262144, 262144, 1024, 1024, 65536, 256, 512, 256, 1,
        1028, 4, 4, 4
    };
    ushort_t* ptrs[23];
    long off = 0;
    for (int i = 0; i < 23; ++i) {
        ptrs[i] = base + off;
        off += (sizes[i] + 7) & ~7L;   // 16B-aligned layout
    }

    WsPtrs wp;
    wp.wcfg = ptrs[0];  wp.bcfg = ptrs[1];  wp.eh   = ptrs[2];  wp.ew   = ptrs[3];
    wp.es   = ptrs[4];  wp.wis  = ptrs[5];  wp.bis  = ptrs[6];  wp.wes  = ptrs[7];
    wp.vds  = ptrs[8];  wp.bvds = ptrs[9];  wp.whh  = ptrs[10]; wp.wih  = ptrs[11];
    wp.bih  = ptrs[12]; wp.bhh  = ptrs[13]; wp.wdt  = ptrs[14]; wp.bdt  = ptrs[15];
    wp.wd2t = ptrs[16]; wp.vdt  = ptrs[17]; wp.bvdt = ptrs[18]; wp.wihd = ptrs[19];
    wp.whhd = ptrs[20]; wp.bihd = ptrs[21]; wp.bhhd = ptrs[22];

    ushort_t* inputs = base + off;            // MT*256
    ushort_t* wib    = inputs + MT * 256;     // MT*256
    ushort_t* midb   = wib + MT * 256;        // MT*256
    ushort_t* axb    = midb + MT * 256;       // MT*1024 (201 MB): AX = x@Wih.T
    ushort_t* wdb    = wib;                   // alias: wi dead after encoder

    k_detect<<<1, 64, 0, stream>>>(d_in[3], flagp);
    k_cvt<<<23, 256, 0, stream>>>(sp, wp, flagp);
    k_permA<<<dim3(128, 2), 256, 0, stream>>>(d_in[9], d_in[8], wp.whh, wp.wih, flagp);
    k_permB<<<64, 256, 0, stream>>>(d_in[18], wp.wes, flagp);
    k_build<<<24576, 256, 0, stream>>>(d_in[0], d_in[1], (const int*)d_in[2],
                                       wp, flagp, inputs);
    k_gemm<<<dim3(768, 2), 256, 0, stream>>>(inputs, wp.wis, wp.bis, wib, 256, 0);
    k_gemm<<<dim3(768, 8), 256, 0, stream>>>(inputs, wp.wih, nullptr, axb, 1024, 1);
    k_encoder<<<64, 1024, 0, stream>>>(wib, axb, wp, midb);
    k_gemm<<<dim3(768, 2), 256, 0, stream>>>(midb, wp.wdt, wp.bdt, wdb, 256, 0);
    k_decoder<<<1024, 256, 0, stream>>>(midb, wdb, wp, flagp, d_out);
}

// Round 4
// 2550.231 us; speedup vs baseline: 1.1189x; 1.0987x over previous
//
#include <hip/hip_runtime.h>
#include <hip/hip_bf16.h>

// ---------------------------------------------------------------------------
// Round 10: encoder weight stream via global_load_lds DMA ring.
//   R8/R9's register-prefetch was collapsed by the allocator (VGPR stuck at
//   64): every weight chunk cost a full serialized L2 RTT (~885cy x 48/step).
//   DMA loads have no register consumer -> cannot be sunk; issue/wait are
//   decoupled via counted s_waitcnt vmcnt(N) (proven T3/T4 pattern).
//   Per-wave 4-slot x 1KB LDS ring; refills stay in flight across the
//   lgkm-only barriers and step boundaries. Fragment-major chunk layout is
//   exactly global_load_lds's base+lane*16 write pattern.
// ---------------------------------------------------------------------------

typedef unsigned short ushort_t;
using short4v = __attribute__((ext_vector_type(4))) short;   // 4 x bf16
using short8  = __attribute__((ext_vector_type(8))) short;   // 8 x bf16
using floatx4 = __attribute__((ext_vector_type(4))) float;   // MFMA accumulator

#define DEVFN static __device__ __forceinline__

DEVFN float bs2f(ushort_t u) {
    union { float f; unsigned v; } c; c.v = ((unsigned)u) << 16; return c.f;
}
DEVFN ushort_t f2bs(float f) {
    __hip_bfloat16 h = __float2bfloat16(f);
    return *reinterpret_cast<ushort_t*>(&h);
}
DEVFN float gload(const void* p, long i, int bf) {
    if (bf) return bs2f(((const ushort_t*)p)[i]);
    return ((const float*)p)[i];
}
DEVFN float sigm(float x) { return 1.f / (1.f + __expf(-x)); }
DEVFN float ftanh(float x) {
    float t = __expf(-2.f * fabsf(x));
    float r = (1.f - t) / (1.f + t);
    return copysignf(r, x);
}
DEVFN short8 ld8(const ushort_t* p) { return *reinterpret_cast<const short8*>(p); }

// publish LDS writes + barrier WITHOUT draining vmcnt (DMA refills stay live)
DEVFN void bar_lgkm() {
    asm volatile("s_waitcnt lgkmcnt(0)" ::: "memory");
    __builtin_amdgcn_s_barrier();
}

// async global->LDS DMA: 64 lanes x 16B. gptr is per-lane, lds base uniform.
DEVFN void gload_lds16(const ushort_t* g, ushort_t* l) {
    typedef const __attribute__((address_space(1))) unsigned int gu32;
    typedef __attribute__((address_space(3))) unsigned int lu32;
    __builtin_amdgcn_global_load_lds((gu32*)g, (lu32*)l, 16, 0, 0);
}

DEVFN const ushort_t* chunk_ptr(const ushort_t* wesW, const ushort_t* whhW, int j) {
    // stream order per step: j 0..15 = wes chunks, 16..47 = whh chunks
    return (j < 16) ? (wesW + (j << 9)) : (whhW + ((j - 16) << 9));
}

struct SrcPtrs { const void* p[26]; };
struct WsPtrs {
    // wes/whh hold PERMUTED (fragment-major) data; wih holds PLAIN bf16
    // row-major Wih_e (GEMM input).
    ushort_t *wcfg, *bcfg, *eh, *ew, *es, *wis, *bis, *wes, *vds, *bvds,
             *whh, *wih, *bih, *bhh, *wdt, *bdt, *wd2t, *vdt, *bvdt,
             *wihd, *whhd, *bihd, *bhhd;
};

// ---------------------------------------------------------------------------
__global__ void k_detect(const void* probe, int* flag) {
    if (threadIdx.x == 0 && blockIdx.x == 0) {
        const ushort_t* u = (const ushort_t*)probe;
        int ok = 1;
        for (int i = 0; i < 16; ++i) {
            ushort_t v = u[2 * i];
            int e = (v >> 7) & 0xFF;
            if (!(v == 0 || (e >= 96 && e <= 126))) ok = 0;
        }
        *flag = ok;
    }
}

// ---------------------------------------------------------------------------
// k_cvt: small tensors only (wes/whh/wih are handled by the perm kernels).
// ---------------------------------------------------------------------------
__global__ __launch_bounds__(256) void k_cvt(SrcPtrs sp, WsPtrs wp, const int* flagp) {
    int bf = *flagp;
    const void* src = nullptr; ushort_t* dst = nullptr; long n = 0;
    switch (blockIdx.x) {
        case 0:  src = sp.p[3];  dst = wp.wcfg; n = 320;    break;
        case 1:  src = sp.p[4];  dst = wp.bcfg; n = 10;     break;
        case 2:  src = sp.p[5];  dst = wp.eh;   n = 120;    break;
        case 3:  src = sp.p[6];  dst = wp.ew;   n = 24;     break;
        case 4:  src = sp.p[7];  dst = wp.es;   n = 15;     break;
        case 5:  src = sp.p[16]; dst = wp.wis;  n = 65536;  break;
        case 6:  src = sp.p[17]; dst = wp.bis;  n = 256;    break;
        case 8:  src = sp.p[19]; dst = wp.vds;  n = 256;    break;
        case 9:  src = sp.p[20]; dst = wp.bvds; n = 1;      break;
        case 12: src = sp.p[10]; dst = wp.bih;  n = 1024;   break;
        case 13: src = sp.p[11]; dst = wp.bhh;  n = 1024;   break;
        case 14: src = sp.p[21]; dst = wp.wdt;  n = 65536;  break;
        case 15: src = sp.p[22]; dst = wp.bdt;  n = 256;    break;
        case 16: src = sp.p[23]; dst = wp.wd2t; n = 512;    break;
        case 17: src = sp.p[24]; dst = wp.vdt;  n = 256;    break;
        case 18: src = sp.p[25]; dst = wp.bvdt; n = 1;      break;
        case 19: src = sp.p[12]; dst = wp.wihd; n = 1028;   break;
        case 20: src = sp.p[13]; dst = wp.whhd; n = 4;      break;
        case 21: src = sp.p[14]; dst = wp.bihd; n = 4;      break;
        case 22: src = sp.p[15]; dst = wp.bhhd; n = 4;      break;
        default: return;
    }
    for (long i = threadIdx.x; i < n; i += 256) {
        float v = bf ? bs2f(((const ushort_t*)src)[i]) : ((const float*)src)[i];
        dst[i] = f2bs(v);
    }
}

// ---------------------------------------------------------------------------
// k_permA: y=0: Whh (1024x256 row-major) -> fragment-major (encoder layout).
//          y=1: Wih -> PLAIN bf16 copy (row-major; consumed by the AX GEMM).
// Fragment-major: dst p: chunk c=p>>9 (512 el = 64 lanes x 8), l=(p>>3)&63,
// e=p&7; c = w*32 + kk*4 + g; src row = g*256+w*16+(l&15),
// src col = kk*32+(l>>4)*8+e.  grid (128, 2), 2048 els/block.
// ---------------------------------------------------------------------------
__global__ __launch_bounds__(256) void k_permA(
    const void* whh_src, const void* wih_src,
    ushort_t* whhp, ushort_t* wihb, const int* flagp)
{
    int bf = *flagp;
    long base = (long)blockIdx.x * 2048;
    if (blockIdx.y == 1) {
#pragma unroll
        for (int ii = 0; ii < 8; ++ii) {
            long p = base + threadIdx.x + ii * 256;
            wihb[p] = f2bs(gload(wih_src, p, bf));
        }
        return;
    }
#pragma unroll
    for (int ii = 0; ii < 8; ++ii) {
        long p = base + threadIdx.x + ii * 256;
        int c = (int)(p >> 9), l = (int)((p >> 3) & 63), e = (int)(p & 7);
        int w = c >> 5, kk = (c >> 2) & 7, g = c & 3;
        int q = l >> 4, ln = l & 15;
        long si = (long)(g * 256 + w * 16 + ln) * 256 + kk * 32 + q * 8 + e;
        whhp[p] = f2bs(gload(whh_src, si, bf));
    }
}

// ---------------------------------------------------------------------------
// k_permB: Wes (256x512 row-major) -> fragment-major. c = w*16 + kk (kk 0..15).
// src row = w*16 + (l&15); src col = kk*32 + (l>>4)*8 + e. grid 64 blocks.
// ---------------------------------------------------------------------------
__global__ __launch_bounds__(256) void k_permB(
    const void* wes_src, ushort_t* wesp, const int* flagp)
{
    int bf = *flagp;
    long base = (long)blockIdx.x * 2048;
#pragma unroll
    for (int ii = 0; ii < 8; ++ii) {
        long p = base + threadIdx.x + ii * 256;
        int c = (int)(p >> 9), l = (int)((p >> 3) & 63), e = (int)(p & 7);
        int w = c >> 4, kk = c & 15;
        int q = l >> 4, ln = l & 15;
        long si = (long)(w * 16 + ln) * 512 + kk * 32 + q * 8 + e;
        wesp[p] = f2bs(gload(wes_src, si, bf));
    }
}

// ---------------------------------------------------------------------------
// k_build: features. 24576 blocks x 256 thr, 4 rows/block.
// ---------------------------------------------------------------------------
__global__ __launch_bounds__(256) void k_build(
    const void* __restrict__ pq, const void* __restrict__ cfg_in,
    const int* __restrict__ timei, WsPtrs wp, const int* __restrict__ flagp,
    ushort_t* __restrict__ inputs)
{
    int bf = *flagp;
    int ch = threadIdx.x;
    for (int rr = 0; rr < 4; ++rr) {
        long row = (long)blockIdx.x * 4 + rr;
        float v;
        if (ch < 235) {
            v = gload(pq, row * 235 + ch, bf);
        } else if (ch < 245) {
            int j = ch - 235;
            float acc = bs2f(wp.bcfg[j]);
            for (int k = 0; k < 32; ++k)
                acc += gload(cfg_in, row * 32 + k, bf) * bs2f(wp.wcfg[j * 32 + k]);
            v = acc;
        } else if (ch < 250) {
            v = bs2f(wp.eh[timei[row * 3 + 0] * 5 + (ch - 245)]);
        } else if (ch < 253) {
            v = bs2f(wp.ew[timei[row * 3 + 1] * 3 + (ch - 250)]);
        } else {
            v = bs2f(wp.es[timei[row * 3 + 2] * 3 + (ch - 253)]);
        }
        inputs[row * 256 + ch] = f2bs(v);
    }
}

// ---------------------------------------------------------------------------
// k_gemm: out = A @ W.T (+ bias). A:(98304x256), W row-major ws bf16, K=256.
// 128x128 tiles, BK=32, 4 waves of 64x64.
//   ostride : output row stride (256 for wi/wd, 1024 for AX)
//   gatherB : when set, output col c corresponds to W row (c&3)*256 + (c>>2)
//   bias==nullptr -> no bias.
// ---------------------------------------------------------------------------
__global__ __launch_bounds__(256) void k_gemm(
    const ushort_t* __restrict__ A, const ushort_t* __restrict__ W,
    const ushort_t* __restrict__ bias, ushort_t* __restrict__ out,
    int ostride, int gatherB)
{
    const int K = 256;
    __shared__ alignas(16) ushort_t At[128][40];
    __shared__ alignas(16) ushort_t Bt[128][40];

    int tid  = threadIdx.x;
    int lane = tid & 63, wave = tid >> 6;
    int wm = wave >> 1, wn = wave & 1;
    int q = lane >> 4, ln = lane & 15;
    long mbase = (long)blockIdx.x * 128;

    floatx4 acc[4][4];
#pragma unroll
    for (int i = 0; i < 4; ++i)
#pragma unroll
        for (int j = 0; j < 4; ++j) acc[i][j] = (floatx4){0.f, 0.f, 0.f, 0.f};

    for (int k0 = 0; k0 < K; k0 += 32) {
        __syncthreads();
#pragma unroll
        for (int it = 0; it < 2; ++it) {
            int c = tid + it * 256;
            int r = c >> 2, kc = (c & 3) * 8;
            int wrow = gatherB ? (((r & 3) << 8) + ((int)blockIdx.y << 5) + (r >> 2))
                               : ((int)blockIdx.y * 128 + r);
            *reinterpret_cast<short8*>(&At[r][kc]) = ld8(&A[(mbase + r) * K + k0 + kc]);
            *reinterpret_cast<short8*>(&Bt[r][kc]) = ld8(&W[(long)wrow * K + k0 + kc]);
        }
        __syncthreads();
        short8 af[4];
#pragma unroll
        for (int mt = 0; mt < 4; ++mt)
            af[mt] = *reinterpret_cast<const short8*>(&At[wm * 64 + mt * 16 + ln][q * 8]);
#pragma unroll
        for (int nt = 0; nt < 4; ++nt) {
            short8 bf = *reinterpret_cast<const short8*>(&Bt[wn * 64 + nt * 16 + ln][q * 8]);
#pragma unroll
            for (int mt = 0; mt < 4; ++mt)
                acc[mt][nt] = __builtin_amdgcn_mfma_f32_16x16x32_bf16(af[mt], bf, acc[mt][nt], 0, 0, 0);
        }
    }

#pragma unroll
    for (int mt = 0; mt < 4; ++mt)
#pragma unroll
        for (int nt = 0; nt < 4; ++nt)
#pragma unroll
            for (int reg = 0; reg < 4; ++reg) {
                long row = mbase + wm * 64 + mt * 16 + q * 4 + reg;
                int  col = (int)blockIdx.y * 128 + wn * 64 + nt * 16 + ln;
                float bv = bias ? bs2f(bias[col]) : 0.f;
                out[row * (long)ostride + col] = f2bs(acc[mt][nt][reg] + bv);
            }
}

// ---------------------------------------------------------------------------
// k_encoder: 64 blocks x 1024 thr (16 waves), 16 batch rows/block, 1 block/CU
// (LDS ~100KB). Weight chunks (48 x 1KB per wave per step) DMA'd via
// global_load_lds into a per-wave 4-slot LDS ring; counted vmcnt keeps 3-4
// refills in flight continuously, across barriers and step boundaries.
// VMEM issue order per step (vmcnt bookkeeping):
//   [prev gates: refills ...,0',1',2',3'] | extras: mid store + 4 ax + 4 wi
//   | attn kk=0..15: wait(kk<4 ? 12 : 3), read slot, MFMA, refill kk+4
//   | barA(lgkm) | gates j=16..47: wait(3), read, MFMA, refill (j+4)%48
//   | aval/cell | barC(lgkm)
// ---------------------------------------------------------------------------
#define MFMA16(a, b, c) __builtin_amdgcn_mfma_f32_16x16x32_bf16((a), (b), (c), 0, 0, 0)

__global__ __launch_bounds__(1024) void k_encoder(
    const ushort_t* __restrict__ wi, const ushort_t* __restrict__ ax,
    WsPtrs wp, ushort_t* __restrict__ mid)
{
    __shared__ ushort_t wring[16][4][512];             // 64 KB DMA ring
    __shared__ alignas(16) ushort_t hcb[2][16][520];   // 33 KB [h|c] dbuf
    __shared__ alignas(16) float aPartT[16][20];       // [wave][row]

    int tid  = threadIdx.x;
    int lane = tid & 63, w = tid >> 6;                 // w in [0,16)
    int q = lane >> 4, ln = lane & 15;
    int u = w * 16 + ln;                               // owned column
    long row0 = (long)blockIdx.x * 16;

    for (int i = tid; i < 2 * 16 * 520; i += 1024) ((ushort_t*)hcb)[i] = 0;

    // per-thread invariants
    float bc0 = bs2f(wp.bih[u])       + bs2f(wp.bhh[u]);
    float bc1 = bs2f(wp.bih[256 + u]) + bs2f(wp.bhh[256 + u]);
    float bc2 = bs2f(wp.bih[512 + u]) + bs2f(wp.bhh[512 + u]);
    float bc3 = bs2f(wp.bih[768 + u]) + bs2f(wp.bhh[768 + u]);
    float vds = bs2f(wp.vds[u]);
    float bVd = bs2f(wp.bvds[0]);

    const ushort_t* wesW = wp.wes + ((long)w << 13) + lane * 8;   // 16 chunks
    const ushort_t* whhW = wp.whh + ((long)w << 14) + lane * 8;   // 32 chunks

    const ushort_t* wiB[4]; const ushort_t* axB[4];
#pragma unroll
    for (int reg = 0; reg < 4; ++reg) {
        long rw = (row0 + q * 4 + reg) * 96;
        wiB[reg] = wi + rw * 256 + u;
        axB[reg] = ax + rw * 1024 + u * 4;
    }
    int mr = tid >> 6, mc = (tid & 63) * 4;            // mid-writer mapping
    ushort_t* midB = mid + (row0 + mr) * 96 * 256 + mc;

    float creg[4] = {0.f, 0.f, 0.f, 0.f};
    __syncthreads();

    // ---- ring prologue: stage chunks 0..3 (wes) for t=0
#pragma unroll
    for (int j = 0; j < 4; ++j)
        gload_lds16(wesW + (j << 9), &wring[w][j][0]);

    for (int t = 0; t < 96; ++t) {
        ushort_t (*R)[520]  = hcb[t & 1];
        ushort_t (*Wb)[520] = hcb[(t & 1) ^ 1];

        // ---- extras (9 VMEM ops, unconditional for stable vmcnt counts):
        // mid write of step t-1 (t=0: dummy write to slot 95, overwritten by
        // the final write), then ax (4x8B) + wi (4x2B) prefetch.
        {
            long toff = (long)(t > 0 ? t - 1 : 95) * 256;
            uint2 hv = *reinterpret_cast<const uint2*>(&R[mr][mc]);
            *reinterpret_cast<uint2*>(midB + toff) = hv;
        }
        short4v axv[4]; float wiv[4];
#pragma unroll
        for (int reg = 0; reg < 4; ++reg) {
            axv[reg] = *reinterpret_cast<const short4v*>(axB[reg] + (long)t * 1024);
            wiv[reg] = bs2f(wiB[reg][(long)t * 256]);
        }

        // ---- attn matvec: K=512 over [h|c], chunks 0..15 (wes)
        floatx4 acc1 = (floatx4){0.f, 0.f, 0.f, 0.f};
#pragma unroll
        for (int kk = 0; kk < 16; ++kk) {
            if (kk < 4) asm volatile("s_waitcnt vmcnt(12)" ::: "memory");
            else        asm volatile("s_waitcnt vmcnt(3)"  ::: "memory");
            short8 bw = ld8(&wring[w][kk & 3][lane * 8]);
            short8 af = ld8(&R[ln][kk * 32 + q * 8]);
            acc1 = MFMA16(af, bw, acc1);
            gload_lds16(chunk_ptr(wesW, whhW, kk + 4), &wring[w][kk & 3][0]);
        }

        // ---- attn epilogue: tanh, scale, reduce over 16 ln lanes
        float p4[4];
#pragma unroll
        for (int reg = 0; reg < 4; ++reg)
            p4[reg] = ftanh(acc1[reg] + wiv[reg]) * vds;
#pragma unroll
        for (int m = 1; m < 16; m <<= 1) {
#pragma unroll
            for (int reg = 0; reg < 4; ++reg) p4[reg] += __shfl_xor(p4[reg], m, 64);
        }
        if (ln == 0) {
            floatx4 pv = {p4[0], p4[1], p4[2], p4[3]};
            *reinterpret_cast<floatx4*>(&aPartT[w][q * 4]) = pv;
        }
        bar_lgkm();   // barrier A: aPartT visible (DMA refills stay live)

        // ---- gates: aH = h@Whh.T; chunks 16..47 (whh), chunk(kk,g)=16+kk*4+g
        floatx4 aH[4];
#pragma unroll
        for (int g = 0; g < 4; ++g) aH[g] = (floatx4){0.f, 0.f, 0.f, 0.f};
#pragma unroll
        for (int kk = 0; kk < 8; ++kk) {
            short8 af = ld8(&R[ln][kk * 32 + q * 8]);
#pragma unroll
            for (int g = 0; g < 4; ++g) {
                const int j  = 16 + kk * 4 + g;
                const int jn = (j + 4 < 48) ? (j + 4) : (j + 4 - 48);
                asm volatile("s_waitcnt vmcnt(3)" ::: "memory");
                short8 bw = ld8(&wring[w][j & 3][lane * 8]);
                aH[g] = MFMA16(af, bw, aH[g]);
                gload_lds16(chunk_ptr(wesW, whhW, jn), &wring[w][j & 3][0]);
            }
        }

        // ---- aval: per-row sum of 16 wave partials (broadcast b128 reads)
        floatx4 av = {bVd, bVd, bVd, bVd};
#pragma unroll
        for (int ww = 0; ww < 16; ++ww)
            av += *reinterpret_cast<const floatx4*>(&aPartT[ww][q * 4]);

        // ---- cell update: rows q*4+reg, col u; write into Wb
#pragma unroll
        for (int reg = 0; reg < 4; ++reg) {
            float a  = av[reg];
            float gi = aH[0][reg] + a * bs2f((ushort_t)axv[reg][0]) + bc0;
            float gf = aH[1][reg] + a * bs2f((ushort_t)axv[reg][1]) + bc1;
            float gg = aH[2][reg] + a * bs2f((ushort_t)axv[reg][2]) + bc2;
            float go = aH[3][reg] + a * bs2f((ushort_t)axv[reg][3]) + bc3;
            float c2 = sigm(gf) * creg[reg] + sigm(gi) * ftanh(gg);
            float h2 = sigm(go) * ftanh(c2);
            creg[reg] = c2;
            int r = q * 4 + reg;
            Wb[r][u] = f2bs(h2);
            Wb[r][256 + u] = f2bs(c2);
        }
        bar_lgkm();   // barrier C: new state published
    }

    // drain leftover DMA refills before LDS deallocation / final read
    asm volatile("s_waitcnt vmcnt(0)" ::: "memory");

    // final mid write: h_96 lives in hcb[0] (t=95 wrote buffer 0)
    {
        uint2 hv = *reinterpret_cast<const uint2*>(&hcb[0][mr][mc]);
        *reinterpret_cast<uint2*>(midB + 95L * 256) = hv;
    }
}

// ---------------------------------------------------------------------------
// k_decoder: 1024 blocks (one batch row), 256 thr, 16 sequential steps.
// ---------------------------------------------------------------------------
__global__ __launch_bounds__(256) void k_decoder(
    const ushort_t* __restrict__ mid, const ushort_t* __restrict__ wd,
    WsPtrs wp, const int* __restrict__ flagp, void* __restrict__ out)
{
    __shared__ ushort_t wdl[96][264];
    __shared__ float qL[256], aLs[96], ctxL[256], VdtL[256], gL[4];
    __shared__ float st[3];

    int tid = threadIdx.x;
    long b = blockIdx.x;
    int bf = *flagp;

    for (int c = tid; c < 96 * 256; c += 256) {
        int tp = c >> 8, chn = c & 255;
        wdl[tp][chn] = wd[(b * 96 + tp) * 256 + chn];
    }
    qL[tid] = 0.f; ctxL[tid] = 0.f;
    if (tid < 96) aLs[tid] = 0.f;
    if (tid < 4)  gL[tid] = 0.f;
    VdtL[tid] = bs2f(wp.vdt[tid]);
    if (tid == 0) {
        st[0] = 0.f; st[1] = 0.f;
        st[2] = bs2f(mid[(b * 96 + 95) * 256 + 2]);
    }
    float bVdt = bs2f(wp.bvdt[0]);
    float w2a = bs2f(wp.wd2t[tid * 2]), w2b = bs2f(wp.wd2t[tid * 2 + 1]);
    __syncthreads();

    for (int s = 0; s < 16; ++s) {
        float hi = st[0], ci = st[1], prev = st[2];
        qL[tid] = hi * w2a + ci * w2b;
        __syncthreads();
        {   // attn scores: wave v, lanes split the 256-dot
            int v = tid >> 6, l = tid & 63;
            for (int tp = v; tp < 96; tp += 4) {
                float sacc = 0.f;
#pragma unroll
                for (int e = 0; e < 4; ++e) {
                    int u = l * 4 + e;
                    sacc += ftanh(qL[u] + bs2f(wdl[tp][u])) * VdtL[u];
                }
#pragma unroll
                for (int m = 1; m < 64; m <<= 1) sacc += __shfl_xor(sacc, m, 64);
                if (l == 0) aLs[tp] = sacc + bVdt;
            }
        }
        __syncthreads();
        {
            float acc = 0.f;
            for (int tp = 0; tp < 96; ++tp)
                acc += aLs[tp] * bs2f(mid[(b * 96 + tp) * 256 + tid]);
            ctxL[tid] = acc;
        }
        __syncthreads();
        {   // gates: wave g computes gate g; lanes split the ctx-dot
            int g = tid >> 6, k = tid & 63;
            float part = 0.f;
#pragma unroll
            for (int e = 0; e < 4; ++e) {
                int u = k + e * 64;
                part += bs2f(wp.wihd[g * 257 + u]) * ctxL[u];
            }
#pragma unroll
            for (int m = 1; m < 64; m <<= 1) part += __shfl_xor(part, m, 64);
            if (k == 0)
                gL[g] = part + bs2f(wp.bihd[g]) + bs2f(wp.bhhd[g])
                      + bs2f(wp.whhd[g]) * hi + bs2f(wp.wihd[g * 257 + 256]) * prev;
        }
        __syncthreads();
        if (tid == 0) {
            float c2 = sigm(gL[1]) * ci + sigm(gL[0]) * ftanh(gL[2]);
            float h2 = sigm(gL[3]) * ftanh(c2);
            st[0] = h2; st[1] = c2; st[2] = h2;
            long oi = b * 16 + s;
            if (bf) ((ushort_t*)out)[oi] = f2bs(h2);
            else    ((float*)out)[oi] = h2;
        }
        __syncthreads();
    }
}

// ---------------------------------------------------------------------------
extern "C" void kernel_launch(void* const* d_in, const int* in_sizes, int n_in,
                              void* d_out, int out_size, void* d_ws, size_t ws_size,
                              hipStream_t stream)
{
    const long MT = 1024L * 96;   // 98304 rows

    int* flagp = (int*)d_ws;
    ushort_t* base = (ushort_t*)((char*)d_ws + 256);

    SrcPtrs sp;
    for (int i = 0; i < 26; ++i) sp.p[i] = d_in[i];

    static const long sizes[23] = {
        320, 10, 120, 24, 15, 65536, 256, 131072, 256, 1,
        262144, 262144, 1024, 1024, 65536, 256, 512, 256, 1,
        1028, 4, 4, 4
    };
    ushort_t* ptrs[23];
    long off = 0;
    for (int i = 0; i < 23; ++i) {
        ptrs[i] = base + off;
        off += (sizes[i] + 7) & ~7L;   // 16B-aligned layout
    }

    WsPtrs wp;
    wp.wcfg = ptrs[0];  wp.bcfg = ptrs[1];  wp.eh   = ptrs[2];  wp.ew   = ptrs[3];
    wp.es   = ptrs[4];  wp.wis  = ptrs[5];  wp.bis  = ptrs[6];  wp.wes  = ptrs[7];
    wp.vds  = ptrs[8];  wp.bvds = ptrs[9];  wp.whh  = ptrs[10]; wp.wih  = ptrs[11];
    wp.bih  = ptrs[12]; wp.bhh  = ptrs[13]; wp.wdt  = ptrs[14]; wp.bdt  = ptrs[15];
    wp.wd2t = ptrs[16]; wp.vdt  = ptrs[17]; wp.bvdt = ptrs[18]; wp.wihd = ptrs[19];
    wp.whhd = ptrs[20]; wp.bihd = ptrs[21]; wp.bhhd = ptrs[22];

    ushort_t* inputs = base + off;            // MT*256
    ushort_t* wib    = inputs + MT * 256;     // MT*256
    ushort_t* midb   = wib + MT * 256;        // MT*256
    ushort_t* axb    = midb + MT * 256;       // MT*1024 (201 MB): AX = x@Wih.T
    ushort_t* wdb    = wib;                   // alias: wi dead after encoder

    k_detect<<<1, 64, 0, stream>>>(d_in[3], flagp);
    k_cvt<<<23, 256, 0, stream>>>(sp, wp, flagp);
    k_permA<<<dim3(128, 2), 256, 0, stream>>>(d_in[9], d_in[8], wp.whh, wp.wih, flagp);
    k_permB<<<64, 256, 0, stream>>>(d_in[18], wp.wes, flagp);
    k_build<<<24576, 256, 0, stream>>>(d_in[0], d_in[1], (const int*)d_in[2],
                                       wp, flagp, inputs);
    k_gemm<<<dim3(768, 2), 256, 0, stream>>>(inputs, wp.wis, wp.bis, wib, 256, 0);
    k_gemm<<<dim3(768, 8), 256, 0, stream>>>(inputs, wp.wih, nullptr, axb, 1024, 1);
    k_encoder<<<64, 1024, 0, stream>>>(wib, axb, wp, midb);
    k_gemm<<<dim3(768, 2), 256, 0, stream>>>(midb, wp.wdt, wp.bdt, wdb, 256, 0);
    k_decoder<<<1024, 256, 0, stream>>>(midb, wdb, wp, flagp, d_out);
}